// Round 1
// baseline (495.765 us; speedup 1.0000x reference)
//
#include <hip/hip_runtime.h>
#include <math.h>

#define N_NODES 100000
#define C 64           // in_c == out_c == 64
#define EPS 1e-9f

// ---------------------------------------------------------------------------
// K2: edge scatter. One wave (64 lanes) per edge; lane = channel.
// Coalesced 256B gather of x[src], 64 atomicAdds into agg[dst].
// ---------------------------------------------------------------------------
__global__ void scatter_mean_kernel(const float* __restrict__ x,
                                    const int* __restrict__ src,
                                    const int* __restrict__ dst,
                                    float* __restrict__ agg,
                                    float* __restrict__ cnt,
                                    int E) {
    const int lane = threadIdx.x & 63;
    const int wave0 = (blockIdx.x * blockDim.x + threadIdx.x) >> 6;
    const int nwaves = (gridDim.x * blockDim.x) >> 6;
    for (int e = wave0; e < E; e += nwaves) {
        int s = src[e];
        int d = dst[e];
        float v = x[(size_t)s * C + lane];
        atomicAdd(&agg[(size_t)d * C + lane], v);
        if (lane == 0) atomicAdd(&cnt[d], 1.0f);
    }
}

// ---------------------------------------------------------------------------
// K3: per-node fused:  agg/count -> lin_l + b + lin_r(x) -> relu -> L2 norm.
// One wave per node; lane = output channel. Weights staged TRANSPOSED in LDS
// with +1 padding: WT[k][lane] reads are stride-1 across lanes (conflict-free),
// row broadcasts are same-address (free).
// ---------------------------------------------------------------------------
__global__ void transform_kernel(const float* __restrict__ x,
                                 const float* __restrict__ agg,
                                 const float* __restrict__ cnt,
                                 const float* __restrict__ Wl,
                                 const float* __restrict__ bl,
                                 const float* __restrict__ Wr,
                                 float* __restrict__ out) {
    __shared__ float WT_l[C][C + 1];
    __shared__ float WT_r[C][C + 1];
    __shared__ float rowA[4][C];
    __shared__ float rowX[4][C];

    const int tid = threadIdx.x;
    // stage weights transposed: WT[k][c] = W[c][k]
    for (int t = tid; t < C * C; t += blockDim.x) {
        int c = t >> 6;
        int k = t & 63;
        WT_l[k][c] = Wl[t];
        WT_r[k][c] = Wr[t];
    }
    __syncthreads();

    const int wid = tid >> 6;
    const int lane = tid & 63;
    const int nwaves_per_blk = blockDim.x >> 6;   // 4
    const float bias = bl[lane];

    for (int n = blockIdx.x * nwaves_per_blk + wid; n < N_NODES;
         n += gridDim.x * nwaves_per_blk) {
        float cn  = cnt[n];
        float inv = 1.0f / fmaxf(cn, 1.0f);
        float a   = agg[(size_t)n * C + lane] * inv;
        float xv  = x[(size_t)n * C + lane];
        // wave-local staging (no barrier needed: same-wave LDS ops are ordered)
        rowA[wid][lane] = a;
        rowX[wid][lane] = xv;

        float acc = bias;
#pragma unroll
        for (int k = 0; k < C; ++k) {
            acc = fmaf(rowA[wid][k], WT_l[k][lane], acc);
            acc = fmaf(rowX[wid][k], WT_r[k][lane], acc);
        }
        acc = fmaxf(acc, 0.0f);

        // 64-lane butterfly reduce of sum of squares
        float sq = acc * acc;
#pragma unroll
        for (int off = 32; off > 0; off >>= 1)
            sq += __shfl_xor(sq, off);

        out[(size_t)n * C + lane] = acc / (sqrtf(sq) + EPS);
    }
}

extern "C" void kernel_launch(void* const* d_in, const int* in_sizes, int n_in,
                              void* d_out, int out_size, void* d_ws, size_t ws_size,
                              hipStream_t stream) {
    const float* x    = (const float*)d_in[0];
    const int*   edge = (const int*)d_in[1];
    const float* Wl   = (const float*)d_in[2];
    const float* bl   = (const float*)d_in[3];
    const float* Wr   = (const float*)d_in[4];
    float*       out  = (float*)d_out;

    const int E = in_sizes[1] / 2;
    const int* src = edge;          // edge_index[0]
    const int* dst = edge + E;      // edge_index[1]

    float* agg = (float*)d_ws;                       // [N_NODES * C]
    float* cnt = agg + (size_t)N_NODES * C;          // [N_NODES]

    // zero accumulators (memset node is graph-capture safe)
    hipMemsetAsync(d_ws, 0, ((size_t)N_NODES * C + N_NODES) * sizeof(float), stream);

    scatter_mean_kernel<<<16384, 256, 0, stream>>>(x, src, dst, agg, cnt, E);
    transform_kernel<<<2048, 256, 0, stream>>>(x, agg, cnt, Wl, bl, Wr, out);
}

// Round 2
// 486.835 us; speedup vs baseline: 1.0183x; 1.0183x over previous
//
#include <hip/hip_runtime.h>
#include <math.h>

#define N_NODES 100000
#define C 64
#define EPS 1e-9f
#define SCAN_BLK 1024
#define NBLK ((N_NODES + SCAN_BLK - 1) / SCAN_BLK)   // 98

// ---------------------------------------------------------------------------
// K1: histogram of dst -> cnt[]
// ---------------------------------------------------------------------------
__global__ void hist_kernel(const int* __restrict__ dst, int* __restrict__ cnt, int E) {
    int stride = gridDim.x * blockDim.x;
    for (int i = blockIdx.x * blockDim.x + threadIdx.x; i < E; i += stride)
        atomicAdd(&cnt[dst[i]], 1);
}

// ---------------------------------------------------------------------------
// K2a: per-block exclusive scan of cnt -> off, block totals -> bsum
// ---------------------------------------------------------------------------
__global__ void scan_block_kernel(const int* __restrict__ cnt, int* __restrict__ off,
                                  int* __restrict__ bsum, int n) {
    __shared__ int tmp[SCAN_BLK];
    int tid = threadIdx.x;
    int gid = blockIdx.x * SCAN_BLK + tid;
    int v = (gid < n) ? cnt[gid] : 0;
    tmp[tid] = v;
    __syncthreads();
    for (int d = 1; d < SCAN_BLK; d <<= 1) {
        int t = (tid >= d) ? tmp[tid - d] : 0;
        __syncthreads();
        tmp[tid] += t;
        __syncthreads();
    }
    if (gid < n) off[gid] = tmp[tid] - v;            // exclusive within block
    if (tid == SCAN_BLK - 1) bsum[blockIdx.x] = tmp[tid];
}

// ---------------------------------------------------------------------------
// K2b: exclusive scan of block sums (single block, 128 threads >= NBLK)
// ---------------------------------------------------------------------------
__global__ void scan_bsum_kernel(int* __restrict__ bsum, int nb) {
    __shared__ int tmp[128];
    int tid = threadIdx.x;
    int v = (tid < nb) ? bsum[tid] : 0;
    tmp[tid] = v;
    __syncthreads();
    for (int d = 1; d < 128; d <<= 1) {
        int t = (tid >= d) ? tmp[tid - d] : 0;
        __syncthreads();
        tmp[tid] += t;
        __syncthreads();
    }
    if (tid < nb) bsum[tid] = tmp[tid] - v;          // exclusive
}

// ---------------------------------------------------------------------------
// K2c: add block offsets; set off[N] = E
// ---------------------------------------------------------------------------
__global__ void scan_add_kernel(int* __restrict__ off, const int* __restrict__ bsum,
                                int n, int E) {
    int gid = blockIdx.x * SCAN_BLK + threadIdx.x;
    if (gid < n) off[gid] += bsum[blockIdx.x];
    if (gid == 0) off[n] = E;
}

// ---------------------------------------------------------------------------
// K3: CSR build. pos = off[d] + cursor[d]++ ; csr[pos] = src
// ---------------------------------------------------------------------------
__global__ void build_kernel(const int* __restrict__ src, const int* __restrict__ dst,
                             const int* __restrict__ off, int* __restrict__ cursor,
                             int* __restrict__ csr, int E) {
    int stride = gridDim.x * blockDim.x;
    for (int i = blockIdx.x * blockDim.x + threadIdx.x; i < E; i += stride) {
        int d = dst[i];
        int p = off[d] + atomicAdd(&cursor[d], 1);
        csr[p] = src[i];
    }
}

// ---------------------------------------------------------------------------
// K4: fused per-node: CSR gather-mean -> lin_l + b + lin_r -> relu -> L2 norm.
// One wave per node, lane = channel. Weights transposed in LDS (+1 pad).
// Row broadcast via __shfl with constant index (v_readlane, no LDS).
// ---------------------------------------------------------------------------
__global__ void __launch_bounds__(1024)
fused_kernel(const float* __restrict__ x, const int* __restrict__ off,
             const int* __restrict__ csr,
             const float* __restrict__ Wl, const float* __restrict__ bl,
             const float* __restrict__ Wr, float* __restrict__ out) {
    __shared__ float WT_l[C][C + 1];
    __shared__ float WT_r[C][C + 1];

    const int tid = threadIdx.x;
    for (int t = tid; t < C * C; t += blockDim.x) {
        int c = t >> 6;
        int k = t & 63;
        WT_l[k][c] = Wl[t];
        WT_r[k][c] = Wr[t];
    }
    __syncthreads();

    const int wid = tid >> 6;
    const int lane = tid & 63;
    const int waves_per_blk = blockDim.x >> 6;       // 16
    const float bias = bl[lane];

    for (int n = blockIdx.x * waves_per_blk + wid; n < N_NODES;
         n += gridDim.x * waves_per_blk) {
        int o0 = off[n];
        int o1 = off[n + 1];
        int deg = o1 - o0;

        float sum = 0.0f;
        int j = o0;
        for (; j + 4 <= o1; j += 4) {
            int s0 = csr[j + 0], s1 = csr[j + 1], s2 = csr[j + 2], s3 = csr[j + 3];
            float v0 = x[(size_t)s0 * C + lane];
            float v1 = x[(size_t)s1 * C + lane];
            float v2 = x[(size_t)s2 * C + lane];
            float v3 = x[(size_t)s3 * C + lane];
            sum += (v0 + v1) + (v2 + v3);
        }
        for (; j < o1; ++j) sum += x[(size_t)csr[j] * C + lane];

        float inv = 1.0f / (float)max(deg, 1);
        float a   = sum * inv;
        float xv  = x[(size_t)n * C + lane];

        float acc = bias;
#pragma unroll
        for (int k = 0; k < C; ++k) {
            float ak = __shfl(a, k);
            float xk = __shfl(xv, k);
            acc = fmaf(ak, WT_l[k][lane], acc);
            acc = fmaf(xk, WT_r[k][lane], acc);
        }
        acc = fmaxf(acc, 0.0f);

        float sq = acc * acc;
#pragma unroll
        for (int o = 32; o > 0; o >>= 1)
            sq += __shfl_xor(sq, o);

        out[(size_t)n * C + lane] = acc / (sqrtf(sq) + EPS);
    }
}

extern "C" void kernel_launch(void* const* d_in, const int* in_sizes, int n_in,
                              void* d_out, int out_size, void* d_ws, size_t ws_size,
                              hipStream_t stream) {
    const float* x    = (const float*)d_in[0];
    const int*   edge = (const int*)d_in[1];
    const float* Wl   = (const float*)d_in[2];
    const float* bl   = (const float*)d_in[3];
    const float* Wr   = (const float*)d_in[4];
    float*       out  = (float*)d_out;

    const int E = in_sizes[1] / 2;
    const int* src = edge;
    const int* dst = edge + E;

    int* cnt    = (int*)d_ws;                 // [N]
    int* cursor = cnt + N_NODES;              // [N]
    int* off    = cursor + N_NODES;           // [N+1]
    int* bsum   = off + N_NODES + 1;          // [128]
    int* csr    = bsum + 128;                 // [E]

    // zero cnt + cursor (adjacent)
    hipMemsetAsync(d_ws, 0, (size_t)2 * N_NODES * sizeof(int), stream);

    hist_kernel<<<2048, 256, 0, stream>>>(dst, cnt, E);
    scan_block_kernel<<<NBLK, SCAN_BLK, 0, stream>>>(cnt, off, bsum, N_NODES);
    scan_bsum_kernel<<<1, 128, 0, stream>>>(bsum, NBLK);
    scan_add_kernel<<<NBLK, SCAN_BLK, 0, stream>>>(off, bsum, N_NODES, E);
    build_kernel<<<2048, 256, 0, stream>>>(src, dst, off, cursor, csr, E);
    fused_kernel<<<512, 1024, 0, stream>>>(x, off, csr, Wl, bl, Wr, out);
}